// Round 21
// baseline (117.727 us; speedup 1.0000x reference)
//
#include <hip/hip_runtime.h>
#include <hip/hip_fp16.h>

#define NN 50000
#define NE 800000
#define NB 16384

#define NBKT 784          // buckets of 64 node ids (784*64 = 50176 >= NN)
#define BCAP 1280         // per-bucket capacity (mean 1020, +8 sigma)
#define CAPL 8            // LDS staging depth per bucket per binning block
#define CNTB 128          // global-histogram blocks
#define P1B  256          // binning blocks
#define DNNB 256          // DNN gemm blocks (64 rows each)

typedef unsigned int uint;
typedef unsigned short ushort;

__device__ __forceinline__ uint pack2h(float a, float b) {
    return (uint)__half_as_ushort(__float2half_rn(a)) |
           ((uint)__half_as_ushort(__float2half_rn(b)) << 16);
}
__device__ __forceinline__ float h2f(ushort u) {
    return __half2float(__ushort_as_half(u));
}

// ---------------- zero the counters (runtime fill kernel is pathological) ------
__global__ void zero_kernel(int* __restrict__ p, int n)
{
    for (int i = blockIdx.x * 256 + threadIdx.x; i < n; i += gridDim.x * 256)
        p[i] = 0;
}

// ---------------- megakernel: cnt + bin (2-pass) + DNN GEMM(+BN) + GCN GEMM ----
// Blocks [0,128): global in-degree histogram ; [128,384): binning ;
// [384,640): DNN ; [640,1424): GCN1. All mutually independent.
struct BinSh {
    uint st[NBKT * CAPL];                       // 25 KiB
    int lc[NBKT];                               // 3.1 KiB
};
union MegaSh {
    BinSh b;                                    // 28.2 KiB
    float xs[64 * 65];                          // 16.6 KiB (GEMM branches)
};

__global__ __launch_bounds__(512) void mega(const int* __restrict__ ei,
    uint* __restrict__ bufC, uint* __restrict__ bufR,
    int* __restrict__ gcurC, int* __restrict__ gcurR,
    int* __restrict__ cntg,
    const float* __restrict__ X1, const float* __restrict__ Wd,
    float* __restrict__ H, float* __restrict__ bnsum,
    float* __restrict__ bnsumsq,
    const float* __restrict__ X2, const float* __restrict__ W1,
    ushort* __restrict__ Hh)
{
    __shared__ MegaSh sh;
    const int tid = threadIdx.x;
    const int lane = tid & 63;
    const int wv = __builtin_amdgcn_readfirstlane(tid >> 6);   // 0..7

    if (blockIdx.x < CNTB) {
        // ---- global in-degree histogram: cntg[c] += 1 ----
        for (int e = blockIdx.x * 512 + tid; e < NE; e += CNTB * 512)
            atomicAdd(&cntg[ei[NE + e]], 1);
        return;
    }

    if (blockIdx.x < CNTB + P1B) {
        BinSh& B = sh.b;
        const int bid = blockIdx.x - CNTB;
        const int per = (NE + P1B - 1) / P1B;
        const int lo = bid * per;
        const int hi = (lo + per < NE) ? lo + per : NE;
        // ---- pass 1: bin by col>>6, ent = (r<<6)|(c&63) ----
        for (int i = tid; i < NBKT; i += 512) B.lc[i] = 0;
        __syncthreads();
        for (int e = lo + tid; e < hi; e += 512) {
            int r = ei[e], c = ei[NE + e];
            uint ent = ((uint)r << 6) | (uint)(c & 63);
            int b = c >> 6;
            int pos = atomicAdd(&B.lc[b], 1);
            if (pos < CAPL) B.st[b * CAPL + pos] = ent;
            else { int gp = atomicAdd(&gcurC[b], 1); bufC[(size_t)b * BCAP + gp] = ent; }
        }
        __syncthreads();
        for (int base = wv * 8; base < NBKT; base += 64) {
            int wb = base + (lane >> 3);
            int idx = lane & 7;
            int n = B.lc[wb]; if (n > CAPL) n = CAPL;
            int gb = 0;
            if (idx == 0 && n > 0) gb = atomicAdd(&gcurC[wb], n);
            gb = __shfl(gb, lane & 56);
            if (idx < n) bufC[(size_t)wb * BCAP + gb + idx] = B.st[wb * CAPL + idx];
        }
        __syncthreads();
        // ---- pass 2: bin by row>>6, ent = ((r&63)<<16)|c ----
        for (int i = tid; i < NBKT; i += 512) B.lc[i] = 0;
        __syncthreads();
        for (int e = lo + tid; e < hi; e += 512) {
            int r = ei[e], c = ei[NE + e];
            uint ent = ((uint)(r & 63) << 16) | (uint)c;
            int rb = r >> 6;
            int pos = atomicAdd(&B.lc[rb], 1);
            if (pos < CAPL) B.st[rb * CAPL + pos] = ent;
            else { int gp = atomicAdd(&gcurR[rb], 1); bufR[(size_t)rb * BCAP + gp] = ent; }
        }
        __syncthreads();
        for (int base = wv * 8; base < NBKT; base += 64) {
            int wb = base + (lane >> 3);
            int idx = lane & 7;
            int n = B.lc[wb]; if (n > CAPL) n = CAPL;
            int gb = 0;
            if (idx == 0 && n > 0) gb = atomicAdd(&gcurR[wb], n);
            gb = __shfl(gb, lane & 56);
            if (idx < n) bufR[(size_t)wb * BCAP + gb + idx] = B.st[wb * CAPL + idx];
        }
        return;
    }

    if (blockIdx.x < CNTB + P1B + DNNB) {
        // ---- DNN: 64 rows, K=256 in 4 staged chunks, lane = row, 8 waves ----
        float* xs = sh.xs;
        const int c0 = wv * 8;
        const int row0 = (blockIdx.x - CNTB - P1B) * 64;
        float acc[8];
#pragma unroll
        for (int j = 0; j < 8; ++j) acc[j] = 0.f;
#pragma unroll 1
        for (int chunk = 0; chunk < 4; ++chunk) {
            if (chunk) __syncthreads();
            for (int i = tid; i < 4096; i += 512) {
                int r = i >> 6, k = i & 63;
                xs[r * 65 + k] = X1[(size_t)(row0 + r) * 256 + chunk * 64 + k];
            }
            __syncthreads();
            const float* xrow = xs + lane * 65;
#pragma unroll
            for (int k4 = 0; k4 < 16; ++k4) {
                float x0 = xrow[4 * k4 + 0];
                float x1 = xrow[4 * k4 + 1];
                float x2 = xrow[4 * k4 + 2];
                float x3 = xrow[4 * k4 + 3];
                const float* wr = Wd + (size_t)(chunk * 64 + 4 * k4) * 64 + c0;
#pragma unroll
                for (int j = 0; j < 8; ++j) {
                    float a = acc[j];
                    a = fmaf(x0, wr[j],       a);
                    a = fmaf(x1, wr[64 + j],  a);
                    a = fmaf(x2, wr[128 + j], a);
                    a = fmaf(x3, wr[192 + j], a);
                    acc[j] = a;
                }
            }
        }
        __syncthreads();
#pragma unroll
        for (int j = 0; j < 8; ++j) xs[lane * 65 + c0 + j] = acc[j];
        __syncthreads();
        float s = 0.f, q = 0.f;
        for (int i = tid; i < 4096; i += 512) {
            int r = i >> 6, c = i & 63;
            float v = xs[r * 65 + c];
            H[(size_t)(row0 + r) * 64 + c] = v;
            s += v; q += v * v;
        }
        __syncthreads();
        float* red = xs;
        red[tid] = s; red[512 + tid] = q;
        __syncthreads();
        if (tid < 64) {
            float ss = 0.f, qq = 0.f;
#pragma unroll
            for (int gidx = 0; gidx < 8; ++gidx) {
                ss += red[gidx * 64 + tid];
                qq += red[512 + gidx * 64 + tid];
            }
            atomicAdd(&bnsum[tid], ss);
            atomicAdd(&bnsumsq[tid], qq);
        }
        return;
    }

    // ---- GCN1: h1h = fp16(x2 @ g1W) UNSCALED, K=64, lane = row, 8 waves ----
    {
        float* xs = sh.xs;
        const int c0 = wv * 8;
        const int row0 = (blockIdx.x - CNTB - P1B - DNNB) * 64;
        float acc[8];
#pragma unroll
        for (int j = 0; j < 8; ++j) acc[j] = 0.f;
        if (row0 + 64 <= NN) {
            for (int i = tid; i < 4096; i += 512) {
                int r = i >> 6, k = i & 63;
                xs[r * 65 + k] = X2[(size_t)(row0 + r) * 64 + k];
            }
        } else {
            for (int i = tid; i < 4096; i += 512) {
                int r = i >> 6, k = i & 63;
                xs[r * 65 + k] = (row0 + r < NN)
                               ? X2[(size_t)(row0 + r) * 64 + k] : 0.f;
            }
        }
        __syncthreads();
        const float* xrow = xs + lane * 65;
#pragma unroll
        for (int k4 = 0; k4 < 16; ++k4) {
            float x0 = xrow[4 * k4 + 0];
            float x1 = xrow[4 * k4 + 1];
            float x2 = xrow[4 * k4 + 2];
            float x3 = xrow[4 * k4 + 3];
            const float* wr = W1 + (size_t)(4 * k4) * 64 + c0;
#pragma unroll
            for (int j = 0; j < 8; ++j) {
                float a = acc[j];
                a = fmaf(x0, wr[j],       a);
                a = fmaf(x1, wr[64 + j],  a);
                a = fmaf(x2, wr[128 + j], a);
                a = fmaf(x3, wr[192 + j], a);
                acc[j] = a;
            }
        }
        __syncthreads();
#pragma unroll
        for (int j = 0; j < 8; ++j) xs[lane * 65 + c0 + j] = acc[j];
        __syncthreads();
        for (int i = tid; i < 2048; i += 512) {
            int r = i >> 5, cp = (i & 31) * 2;
            int row = row0 + r;
            if (row < NN) {
                uint v = pack2h(xs[r * 65 + cp], xs[r * 65 + cp + 1]);
                *reinterpret_cast<uint*>(Hh + (size_t)row * 64 + cp) = v;
            }
        }
    }
}

// ---------------- gather (4 edges/VMEM-instr, unscaled fp16, inline dis) -------
// dis_x = rsqrt(cntg[x]+1). acc = sum_in dis_r*h_r ;
// g_c = dis_c*(acc + dis_c*h_c) + b1 ; coef_c = dis_c*w_c + dis_c^2
__global__ __launch_bounds__(512) void gather_pass(const uint* __restrict__ bufC,
    const int* __restrict__ gcurC, const int* __restrict__ cntg,
    const uint* __restrict__ bufR, const int* __restrict__ gcurR,
    const ushort* __restrict__ hs, const float* __restrict__ b1,
    float* __restrict__ svec)
{
    __shared__ int sorted[BCAP];
    __shared__ int cntS[64], offsS[64], curS[64];
    __shared__ float w[64], disS[64];
    __shared__ float red[8][64];
    const int tid = threadIdx.x;
    const int lane = tid & 63;
    const int wv = __builtin_amdgcn_readfirstlane(tid >> 6);   // 0..7
    const int bb = blockIdx.x;
    const int g4 = lane >> 4;                    // edge sub-group 0..3
    const int l16 = lane & 15;                   // col-quad index
    if (tid < 64) {                              // wave 0: load cnt + scan + dis
        w[tid] = 0.f;
        int v = cntg[bb * 64 + tid];
        cntS[tid] = v;
        disS[tid] = rsqrtf((float)v + 1.0f);
        int s = v;
#pragma unroll
        for (int o = 1; o < 64; o <<= 1) {
            int u = __shfl_up(s, o);
            if (lane >= o) s += u;
        }
        offsS[tid] = s - v;
        curS[tid] = s - v;
    }
    __syncthreads();
    // wraw accumulation from the row-bucket (cntg is a 200 KB L2-resident table)
    const int n2 = gcurR[bb];
    const uint* srcR = bufR + (size_t)bb * BCAP;
    for (int i = tid; i < n2; i += 512) {
        uint e = srcR[i];
        float dc = rsqrtf((float)cntg[e & 0xffffu] + 1.0f);
        atomicAdd(&w[e >> 16], dc);
    }
    // LDS counting-sort scatter of the col-bucket
    const int n = gcurC[bb];
    const uint* src = bufC + (size_t)bb * BCAP;
    for (int i = tid; i < n; i += 512) {
        uint e = src[i];
        int p = atomicAdd(&curS[e & 63u], 1);
        sorted[p] = (int)(e >> 6);
    }
    __syncthreads();
    // each wave: 8 consecutive nodes; 8 edges/iter, uint2 (4 fp16 cols)/lane
    float sacc0 = 0.f, sacc1 = 0.f, sacc2 = 0.f, sacc3 = 0.f;
    const float4 blv = *reinterpret_cast<const float4*>(b1 + (l16 << 2));
#pragma unroll 1
    for (int t = 0; t < 8; ++t) {
        const int nd = wv * 8 + t;
        const int lo = offsS[nd], hi2 = lo + cntS[nd];
        float a0 = 0.f, a1 = 0.f, a2 = 0.f, a3 = 0.f;
        for (int e = lo; e < hi2; e += 8) {
            int i0 = e + g4;
            int i1 = e + 4 + g4;
            int j0 = (i0 < hi2) ? i0 : hi2 - 1;
            int j1 = (i1 < hi2) ? i1 : hi2 - 1;
            float m0 = (i0 < hi2) ? 1.f : 0.f;
            float m1 = (i1 < hi2) ? 1.f : 0.f;
            int r0 = sorted[j0];
            int r1 = sorted[j1];
            float sd0 = m0 * rsqrtf((float)cntg[r0] + 1.0f);
            float sd1 = m1 * rsqrtf((float)cntg[r1] + 1.0f);
            uint2 v0 = *reinterpret_cast<const uint2*>(hs + ((size_t)r0 << 6) + (l16 << 2));
            uint2 v1 = *reinterpret_cast<const uint2*>(hs + ((size_t)r1 << 6) + (l16 << 2));
            a0 = fmaf(sd0, h2f((ushort)(v0.x & 0xffffu)), a0);
            a1 = fmaf(sd0, h2f((ushort)(v0.x >> 16)),     a1);
            a2 = fmaf(sd0, h2f((ushort)(v0.y & 0xffffu)), a2);
            a3 = fmaf(sd0, h2f((ushort)(v0.y >> 16)),     a3);
            a0 = fmaf(sd1, h2f((ushort)(v1.x & 0xffffu)), a0);
            a1 = fmaf(sd1, h2f((ushort)(v1.x >> 16)),     a1);
            a2 = fmaf(sd1, h2f((ushort)(v1.y & 0xffffu)), a2);
            a3 = fmaf(sd1, h2f((ushort)(v1.y >> 16)),     a3);
        }
        // combine the 4 edge sub-groups
        a0 += __shfl_xor(a0, 16); a0 += __shfl_xor(a0, 32);
        a1 += __shfl_xor(a1, 16); a1 += __shfl_xor(a1, 32);
        a2 += __shfl_xor(a2, 16); a2 += __shfl_xor(a2, 32);
        a3 += __shfl_xor(a3, 16); a3 += __shfl_xor(a3, 32);
        const int c = bb * 64 + nd;
        if (c < NN) {
            float d = disS[nd];
            float coef = fmaf(d, w[nd], d * d);
            uint2 sv = *reinterpret_cast<const uint2*>(hs + ((size_t)c << 6) + (l16 << 2));
            float g0 = fmaf(d, fmaf(d, h2f((ushort)(sv.x & 0xffffu)), a0), blv.x);
            float g1 = fmaf(d, fmaf(d, h2f((ushort)(sv.x >> 16)),     a1), blv.y);
            float g2 = fmaf(d, fmaf(d, h2f((ushort)(sv.y & 0xffffu)), a2), blv.z);
            float g3 = fmaf(d, fmaf(d, h2f((ushort)(sv.y >> 16)),     a3), blv.w);
            sacc0 = fmaf(coef, fmaxf(g0, 0.f), sacc0);
            sacc1 = fmaf(coef, fmaxf(g1, 0.f), sacc1);
            sacc2 = fmaf(coef, fmaxf(g2, 0.f), sacc2);
            sacc3 = fmaf(coef, fmaxf(g3, 0.f), sacc3);
        }
    }
    if (g4 == 0) {
        red[wv][(l16 << 2) + 0] = sacc0;
        red[wv][(l16 << 2) + 1] = sacc1;
        red[wv][(l16 << 2) + 2] = sacc2;
        red[wv][(l16 << 2) + 3] = sacc3;
    }
    __syncthreads();
    if (wv == 0) {
        float s = ((red[0][lane] + red[1][lane]) + (red[2][lane] + red[3][lane])) +
                  ((red[4][lane] + red[5][lane]) + (red[6][lane] + red[7][lane]));
        atomicAdd(&svec[lane], s);
    }
}

// ---------------- output + fused finalize --------------------------------------
__global__ __launch_bounds__(256) void out_final(const float* __restrict__ H,
    const float* __restrict__ bnsum, const float* __restrict__ bnsumsq,
    const float* __restrict__ gamma, const float* __restrict__ beta,
    const float* __restrict__ svec, const float* __restrict__ g2W,
    const float* __restrict__ g2b, const float* __restrict__ fc1W,
    const float* __restrict__ fc1b, const float* __restrict__ fc2W,
    const float* __restrict__ fc2b, float* __restrict__ out)
{
    __shared__ float scaleS[64], shiftS[64], vdnnS[64];
    __shared__ float consS;
    const int tid = threadIdx.x;
    const int lane = tid & 63;
    const int grp = tid >> 6;
    if (tid < 64) {                              // wave 0 computes finalize
        int j = tid;
        float mu = bnsum[j] * (1.0f / NB);
        float var = bnsumsq[j] * (1.0f / NB) - mu * mu;
        float sc = rsqrtf(var + 1e-5f) * gamma[j];
        scaleS[j] = sc;
        shiftS[j] = beta[j] - mu * sc;
        float ge = 0.f;
        for (int k = 0; k < 64; ++k) ge += svec[k] * g2W[k * 64 + j];
        ge = ge * (1.0f / NN) + g2b[j];
        float vd = 0.f, vg = 0.f;
        for (int k = 0; k < 64; ++k) {
            vd += fc1W[j * 64 + k] * fc2W[k];
            vg += fc1W[(64 + j) * 64 + k] * fc2W[k];
        }
        vdnnS[j] = vd;
        float part = ge * vg + fc1b[j] * fc2W[j];
#pragma unroll
        for (int o = 32; o > 0; o >>= 1) part += __shfl_down(part, o);
        if (j == 0) consS = part + fc2b[0];
    }
    __syncthreads();
    const float sc = scaleS[lane], sh = shiftS[lane], vd = vdnnS[lane];
    const float C = consS;
#pragma unroll 1
    for (int t = 0; t < 8; ++t) {
        int i = blockIdx.x * 32 + grp * 8 + t;
        float x = H[(size_t)i * 64 + lane] * sc + sh;
        x = fmaxf(x, 0.f) * vd;
#pragma unroll
        for (int o = 32; o > 0; o >>= 1) x += __shfl_down(x, o);
        if (lane == 0) out[i] = x + C;
    }
}

extern "C" void kernel_launch(void* const* d_in, const int* in_sizes, int n_in,
                              void* d_out, int out_size, void* d_ws, size_t ws_size,
                              hipStream_t stream)
{
    const float* x1    = (const float*)d_in[0];
    const float* x2    = (const float*)d_in[1];
    const int*   ei    = (const int*)d_in[2];
    const float* dnnW  = (const float*)d_in[3];
    // d_in[4] = dnn_b: cancels inside BatchNorm, unused
    const float* gamma = (const float*)d_in[5];
    const float* beta  = (const float*)d_in[6];
    const float* g1W   = (const float*)d_in[7];
    const float* g1b   = (const float*)d_in[8];
    const float* g2W   = (const float*)d_in[9];
    const float* g2b   = (const float*)d_in[10];
    const float* fc1W  = (const float*)d_in[11];
    const float* fc1b  = (const float*)d_in[12];
    const float* fc2W  = (const float*)d_in[13];
    const float* fc2b  = (const float*)d_in[14];

    float* ws      = (float*)d_ws;
    ushort* h1h    = (ushort*)ws;                 // occupies 1,605,632 floats
    float* hdnn    = ws + 1605632;                // 1,048,576 f
    uint*  bufC    = (uint*)(hdnn + 1048576);     // 784*1280 = 1,003,520
    uint*  bufR    = bufC + NBKT * BCAP;          // 1,003,520
    int*   gcurC   = (int*)(bufR + NBKT * BCAP);  // 784   <- zero region start
    int*   gcurR   = gcurC + NBKT;                // 784
    float* bnsum   = (float*)(gcurR + NBKT);      // 64
    float* bnsumsq = bnsum + 64;                  // 64
    float* svec    = bnsumsq + 64;                // 64
    int*   cntg    = (int*)(svec + 64);           // 50,176  <- zero region end

    const int ZN = NBKT * 2 + 192 + 50176;        // 51,936 ints
    zero_kernel<<<64, 256, 0, stream>>>(gcurC, ZN);

    mega<<<CNTB + P1B + DNNB + NBKT, 512, 0, stream>>>(
        ei, bufC, bufR, gcurC, gcurR, cntg,
        x1, dnnW, hdnn, bnsum, bnsumsq, x2, g1W, h1h);
    gather_pass<<<NBKT, 512, 0, stream>>>(bufC, gcurC, cntg, bufR, gcurR,
                                          h1h, g1b, svec);
    out_final<<<512, 256, 0, stream>>>(hdnn, bnsum, bnsumsq, gamma, beta, svec,
                                       g2W, g2b, fc1W, fc1b, fc2W, fc2b,
                                       (float*)d_out);
}

// Round 22
// 102.644 us; speedup vs baseline: 1.1470x; 1.1470x over previous
//
#include <hip/hip_runtime.h>
#include <hip/hip_fp16.h>

#define NN 50000
#define NE 800000
#define NB 16384

#define NBKT 784          // buckets of 64 node ids (784*64 = 50176 >= NN)
#define BCAP 1280         // per-bucket capacity (mean 1020, +8 sigma)
#define CAPL 8            // LDS staging depth per bucket per binning block
#define P1B  256          // binning blocks
#define DNNB 256          // DNN gemm blocks (64 rows each)

typedef unsigned int uint;
typedef unsigned short ushort;

__device__ __forceinline__ uint pack2h(float a, float b) {
    return (uint)__half_as_ushort(__float2half_rn(a)) |
           ((uint)__half_as_ushort(__float2half_rn(b)) << 16);
}
__device__ __forceinline__ float h2f(ushort u) {
    return __half2float(__ushort_as_half(u));
}

// ---------------- zero the counters (runtime fill kernel is pathological) ------
__global__ void zero_kernel(int* __restrict__ p, int n)
{
    for (int i = threadIdx.x; i < n; i += 256) p[i] = 0;
}

// ---------------- megakernel: bin (2-pass) + DNN GEMM(+BN) + GCN GEMM ----------
// Blocks [0,256): binning ; [256,512): DNN ; [512,1296): GCN1. All independent.
struct BinSh {
    uint st[NBKT * CAPL];                       // 25 KiB
    int lc[NBKT];                               // 3.1 KiB
};
union MegaSh {
    BinSh b;                                    // 28.2 KiB
    float xs[64 * 65];                          // 16.6 KiB (GEMM branches)
};

__global__ __launch_bounds__(512) void mega(const int* __restrict__ ei,
    uint* __restrict__ bufC, uint* __restrict__ bufR,
    int* __restrict__ gcurC, int* __restrict__ gcurR,
    const float* __restrict__ X1, const float* __restrict__ Wd,
    float* __restrict__ H, float* __restrict__ bnsum,
    float* __restrict__ bnsumsq,
    const float* __restrict__ X2, const float* __restrict__ W1,
    ushort* __restrict__ Hh)
{
    __shared__ MegaSh sh;
    const int tid = threadIdx.x;
    const int lane = tid & 63;
    const int wv = __builtin_amdgcn_readfirstlane(tid >> 6);   // 0..7

    if (blockIdx.x < P1B) {
        BinSh& B = sh.b;
        const int per = (NE + P1B - 1) / P1B;
        const int lo = blockIdx.x * per;
        const int hi = (lo + per < NE) ? lo + per : NE;
        // ---- pass 1: bin by col>>6, ent = (r<<6)|(c&63) ----
        for (int i = tid; i < NBKT; i += 512) B.lc[i] = 0;
        __syncthreads();
        for (int e = lo + tid; e < hi; e += 512) {
            int r = ei[e], c = ei[NE + e];
            uint ent = ((uint)r << 6) | (uint)(c & 63);
            int b = c >> 6;
            int pos = atomicAdd(&B.lc[b], 1);
            if (pos < CAPL) B.st[b * CAPL + pos] = ent;
            else { int gp = atomicAdd(&gcurC[b], 1); bufC[(size_t)b * BCAP + gp] = ent; }
        }
        __syncthreads();
        for (int base = wv * 8; base < NBKT; base += 64) {
            int wb = base + (lane >> 3);
            int idx = lane & 7;
            int n = B.lc[wb]; if (n > CAPL) n = CAPL;
            int gb = 0;
            if (idx == 0 && n > 0) gb = atomicAdd(&gcurC[wb], n);
            gb = __shfl(gb, lane & 56);
            if (idx < n) bufC[(size_t)wb * BCAP + gb + idx] = B.st[wb * CAPL + idx];
        }
        __syncthreads();
        // ---- pass 2: bin by row>>6, ent = ((r&63)<<16)|c ----
        for (int i = tid; i < NBKT; i += 512) B.lc[i] = 0;
        __syncthreads();
        for (int e = lo + tid; e < hi; e += 512) {
            int r = ei[e], c = ei[NE + e];
            uint ent = ((uint)(r & 63) << 16) | (uint)c;
            int rb = r >> 6;
            int pos = atomicAdd(&B.lc[rb], 1);
            if (pos < CAPL) B.st[rb * CAPL + pos] = ent;
            else { int gp = atomicAdd(&gcurR[rb], 1); bufR[(size_t)rb * BCAP + gp] = ent; }
        }
        __syncthreads();
        for (int base = wv * 8; base < NBKT; base += 64) {
            int wb = base + (lane >> 3);
            int idx = lane & 7;
            int n = B.lc[wb]; if (n > CAPL) n = CAPL;
            int gb = 0;
            if (idx == 0 && n > 0) gb = atomicAdd(&gcurR[wb], n);
            gb = __shfl(gb, lane & 56);
            if (idx < n) bufR[(size_t)wb * BCAP + gb + idx] = B.st[wb * CAPL + idx];
        }
        return;
    }

    if (blockIdx.x < P1B + DNNB) {
        // ---- DNN: 64 rows, K=256 in 4 staged chunks, lane = row, 8 waves ----
        float* xs = sh.xs;
        const int c0 = wv * 8;
        const int row0 = (blockIdx.x - P1B) * 64;
        float acc[8];
#pragma unroll
        for (int j = 0; j < 8; ++j) acc[j] = 0.f;
#pragma unroll 1
        for (int chunk = 0; chunk < 4; ++chunk) {
            if (chunk) __syncthreads();
            for (int i = tid; i < 4096; i += 512) {
                int r = i >> 6, k = i & 63;
                xs[r * 65 + k] = X1[(size_t)(row0 + r) * 256 + chunk * 64 + k];
            }
            __syncthreads();
            const float* xrow = xs + lane * 65;
#pragma unroll
            for (int k4 = 0; k4 < 16; ++k4) {
                float x0 = xrow[4 * k4 + 0];
                float x1 = xrow[4 * k4 + 1];
                float x2 = xrow[4 * k4 + 2];
                float x3 = xrow[4 * k4 + 3];
                const float* wr = Wd + (size_t)(chunk * 64 + 4 * k4) * 64 + c0;
#pragma unroll
                for (int j = 0; j < 8; ++j) {
                    float a = acc[j];
                    a = fmaf(x0, wr[j],       a);
                    a = fmaf(x1, wr[64 + j],  a);
                    a = fmaf(x2, wr[128 + j], a);
                    a = fmaf(x3, wr[192 + j], a);
                    acc[j] = a;
                }
            }
        }
        __syncthreads();
#pragma unroll
        for (int j = 0; j < 8; ++j) xs[lane * 65 + c0 + j] = acc[j];
        __syncthreads();
        float s = 0.f, q = 0.f;
        for (int i = tid; i < 4096; i += 512) {
            int r = i >> 6, c = i & 63;
            float v = xs[r * 65 + c];
            H[(size_t)(row0 + r) * 64 + c] = v;
            s += v; q += v * v;
        }
        __syncthreads();
        float* red = xs;
        red[tid] = s; red[512 + tid] = q;
        __syncthreads();
        if (tid < 64) {
            float ss = 0.f, qq = 0.f;
#pragma unroll
            for (int gidx = 0; gidx < 8; ++gidx) {
                ss += red[gidx * 64 + tid];
                qq += red[512 + gidx * 64 + tid];
            }
            atomicAdd(&bnsum[tid], ss);
            atomicAdd(&bnsumsq[tid], qq);
        }
        return;
    }

    // ---- GCN1: h1h = fp16(x2 @ g1W) UNSCALED, K=64, lane = row, 8 waves ----
    {
        float* xs = sh.xs;
        const int c0 = wv * 8;
        const int row0 = (blockIdx.x - P1B - DNNB) * 64;
        float acc[8];
#pragma unroll
        for (int j = 0; j < 8; ++j) acc[j] = 0.f;
        if (row0 + 64 <= NN) {
            for (int i = tid; i < 4096; i += 512) {
                int r = i >> 6, k = i & 63;
                xs[r * 65 + k] = X2[(size_t)(row0 + r) * 64 + k];
            }
        } else {
            for (int i = tid; i < 4096; i += 512) {
                int r = i >> 6, k = i & 63;
                xs[r * 65 + k] = (row0 + r < NN)
                               ? X2[(size_t)(row0 + r) * 64 + k] : 0.f;
            }
        }
        __syncthreads();
        const float* xrow = xs + lane * 65;
#pragma unroll
        for (int k4 = 0; k4 < 16; ++k4) {
            float x0 = xrow[4 * k4 + 0];
            float x1 = xrow[4 * k4 + 1];
            float x2 = xrow[4 * k4 + 2];
            float x3 = xrow[4 * k4 + 3];
            const float* wr = W1 + (size_t)(4 * k4) * 64 + c0;
#pragma unroll
            for (int j = 0; j < 8; ++j) {
                float a = acc[j];
                a = fmaf(x0, wr[j],       a);
                a = fmaf(x1, wr[64 + j],  a);
                a = fmaf(x2, wr[128 + j], a);
                a = fmaf(x3, wr[192 + j], a);
                acc[j] = a;
            }
        }
        __syncthreads();
#pragma unroll
        for (int j = 0; j < 8; ++j) xs[lane * 65 + c0 + j] = acc[j];
        __syncthreads();
        for (int i = tid; i < 2048; i += 512) {
            int r = i >> 5, cp = (i & 31) * 2;
            int row = row0 + r;
            if (row < NN) {
                uint v = pack2h(xs[r * 65 + cp], xs[r * 65 + cp + 1]);
                *reinterpret_cast<uint*>(Hh + (size_t)row * 64 + cp) = v;
            }
        }
    }
}

// ---------------- per-bucket in-degree histogram -> dis, cnth (no scaling) -----
__global__ __launch_bounds__(256) void cnt_dis(const uint* __restrict__ bufC,
    const int* __restrict__ gcurC, float* __restrict__ dis,
    int* __restrict__ cnth)
{
    __shared__ int hist[64];
    const int tid = threadIdx.x, bb = blockIdx.x;
    if (tid < 64) hist[tid] = 0;
    __syncthreads();
    const int n = gcurC[bb];
    const uint* src = bufC + (size_t)bb * BCAP;
    for (int i = tid; i < n; i += 256) atomicAdd(&hist[src[i] & 63], 1);
    __syncthreads();
    if (tid < 64) {
        int c = bb * 64 + tid;
        cnth[bb * 64 + tid] = hist[tid];
        if (c < NN) dis[c] = rsqrtf((float)hist[tid] + 1.0f);
    }
}

// ---------------- gather (4 edges/VMEM-instr, unscaled fp16, per-edge dis) -----
// acc = sum_in dis_r*h_r ; g_c = dis_c*(acc + dis_c*h_c) + b1 ;
// coef_c = dis_c*w_c + dis_c^2
__global__ __launch_bounds__(512) void gather_pass(const uint* __restrict__ bufC,
    const int* __restrict__ gcurC, const int* __restrict__ cnth,
    const uint* __restrict__ bufR, const int* __restrict__ gcurR,
    const float* __restrict__ dis, const ushort* __restrict__ hs,
    const float* __restrict__ b1, float* __restrict__ svec)
{
    __shared__ int sorted[BCAP];
    __shared__ int cntS[64], offsS[64], curS[64];
    __shared__ float w[64], disS[64];
    __shared__ float red[8][64];
    const int tid = threadIdx.x;
    const int lane = tid & 63;
    const int wv = __builtin_amdgcn_readfirstlane(tid >> 6);   // 0..7
    const int bb = blockIdx.x;
    const int g4 = lane >> 4;                    // edge sub-group 0..3
    const int l16 = lane & 15;                   // col-quad index
    if (tid < 64) {                              // wave 0: load hist + scan + dis
        w[tid] = 0.f;
        int v = cnth[bb * 64 + tid];
        cntS[tid] = v;
        disS[tid] = rsqrtf((float)v + 1.0f);
        int s = v;
#pragma unroll
        for (int o = 1; o < 64; o <<= 1) {
            int u = __shfl_up(s, o);
            if (lane >= o) s += u;
        }
        offsS[tid] = s - v;
        curS[tid] = s - v;
    }
    __syncthreads();
    // wraw accumulation from the row-bucket (dis is a 200 KB L2-resident table)
    const int n2 = gcurR[bb];
    const uint* srcR = bufR + (size_t)bb * BCAP;
    for (int i = tid; i < n2; i += 512) {
        uint e = srcR[i];
        atomicAdd(&w[e >> 16], dis[e & 0xffffu]);
    }
    // LDS counting-sort scatter of the col-bucket
    const int n = gcurC[bb];
    const uint* src = bufC + (size_t)bb * BCAP;
    for (int i = tid; i < n; i += 512) {
        uint e = src[i];
        int p = atomicAdd(&curS[e & 63u], 1);
        sorted[p] = (int)(e >> 6);
    }
    __syncthreads();
    // each wave: 8 consecutive nodes; 8 edges/iter, uint2 (4 fp16 cols)/lane
    float sacc0 = 0.f, sacc1 = 0.f, sacc2 = 0.f, sacc3 = 0.f;
    const float4 blv = *reinterpret_cast<const float4*>(b1 + (l16 << 2));
#pragma unroll 1
    for (int t = 0; t < 8; ++t) {
        const int nd = wv * 8 + t;
        const int lo = offsS[nd], hi2 = lo + cntS[nd];
        float a0 = 0.f, a1 = 0.f, a2 = 0.f, a3 = 0.f;
        for (int e = lo; e < hi2; e += 8) {
            int i0 = e + g4;
            int i1 = e + 4 + g4;
            int j0 = (i0 < hi2) ? i0 : hi2 - 1;
            int j1 = (i1 < hi2) ? i1 : hi2 - 1;
            float m0 = (i0 < hi2) ? 1.f : 0.f;
            float m1 = (i1 < hi2) ? 1.f : 0.f;
            int r0 = sorted[j0];
            int r1 = sorted[j1];
            float sd0 = m0 * dis[r0];            // broadcast 4B load (1 txn/group)
            float sd1 = m1 * dis[r1];
            uint2 v0 = *reinterpret_cast<const uint2*>(hs + ((size_t)r0 << 6) + (l16 << 2));
            uint2 v1 = *reinterpret_cast<const uint2*>(hs + ((size_t)r1 << 6) + (l16 << 2));
            a0 = fmaf(sd0, h2f((ushort)(v0.x & 0xffffu)), a0);
            a1 = fmaf(sd0, h2f((ushort)(v0.x >> 16)),     a1);
            a2 = fmaf(sd0, h2f((ushort)(v0.y & 0xffffu)), a2);
            a3 = fmaf(sd0, h2f((ushort)(v0.y >> 16)),     a3);
            a0 = fmaf(sd1, h2f((ushort)(v1.x & 0xffffu)), a0);
            a1 = fmaf(sd1, h2f((ushort)(v1.x >> 16)),     a1);
            a2 = fmaf(sd1, h2f((ushort)(v1.y & 0xffffu)), a2);
            a3 = fmaf(sd1, h2f((ushort)(v1.y >> 16)),     a3);
        }
        // combine the 4 edge sub-groups
        a0 += __shfl_xor(a0, 16); a0 += __shfl_xor(a0, 32);
        a1 += __shfl_xor(a1, 16); a1 += __shfl_xor(a1, 32);
        a2 += __shfl_xor(a2, 16); a2 += __shfl_xor(a2, 32);
        a3 += __shfl_xor(a3, 16); a3 += __shfl_xor(a3, 32);
        const int c = bb * 64 + nd;
        if (c < NN) {
            float d = disS[nd];
            float coef = fmaf(d, w[nd], d * d);
            uint2 sv = *reinterpret_cast<const uint2*>(hs + ((size_t)c << 6) + (l16 << 2));
            float g0 = fmaf(d, fmaf(d, h2f((ushort)(sv.x & 0xffffu)), a0), blv.x);
            float g1 = fmaf(d, fmaf(d, h2f((ushort)(sv.x >> 16)),     a1), blv.y);
            float g2 = fmaf(d, fmaf(d, h2f((ushort)(sv.y & 0xffffu)), a2), blv.z);
            float g3 = fmaf(d, fmaf(d, h2f((ushort)(sv.y >> 16)),     a3), blv.w);
            sacc0 = fmaf(coef, fmaxf(g0, 0.f), sacc0);
            sacc1 = fmaf(coef, fmaxf(g1, 0.f), sacc1);
            sacc2 = fmaf(coef, fmaxf(g2, 0.f), sacc2);
            sacc3 = fmaf(coef, fmaxf(g3, 0.f), sacc3);
        }
    }
    if (g4 == 0) {
        red[wv][(l16 << 2) + 0] = sacc0;
        red[wv][(l16 << 2) + 1] = sacc1;
        red[wv][(l16 << 2) + 2] = sacc2;
        red[wv][(l16 << 2) + 3] = sacc3;
    }
    __syncthreads();
    if (wv == 0) {
        float s = ((red[0][lane] + red[1][lane]) + (red[2][lane] + red[3][lane])) +
                  ((red[4][lane] + red[5][lane]) + (red[6][lane] + red[7][lane]));
        atomicAdd(&svec[lane], s);
    }
}

// ---------------- output + fused finalize --------------------------------------
__global__ __launch_bounds__(256) void out_final(const float* __restrict__ H,
    const float* __restrict__ bnsum, const float* __restrict__ bnsumsq,
    const float* __restrict__ gamma, const float* __restrict__ beta,
    const float* __restrict__ svec, const float* __restrict__ g2W,
    const float* __restrict__ g2b, const float* __restrict__ fc1W,
    const float* __restrict__ fc1b, const float* __restrict__ fc2W,
    const float* __restrict__ fc2b, float* __restrict__ out)
{
    __shared__ float scaleS[64], shiftS[64], vdnnS[64];
    __shared__ float consS;
    const int tid = threadIdx.x;
    const int lane = tid & 63;
    const int grp = tid >> 6;
    if (tid < 64) {                              // wave 0 computes finalize
        int j = tid;
        float mu = bnsum[j] * (1.0f / NB);
        float var = bnsumsq[j] * (1.0f / NB) - mu * mu;
        float sc = rsqrtf(var + 1e-5f) * gamma[j];
        scaleS[j] = sc;
        shiftS[j] = beta[j] - mu * sc;
        float ge = 0.f;
        for (int k = 0; k < 64; ++k) ge += svec[k] * g2W[k * 64 + j];
        ge = ge * (1.0f / NN) + g2b[j];
        float vd = 0.f, vg = 0.f;
        for (int k = 0; k < 64; ++k) {
            vd += fc1W[j * 64 + k] * fc2W[k];
            vg += fc1W[(64 + j) * 64 + k] * fc2W[k];
        }
        vdnnS[j] = vd;
        float part = ge * vg + fc1b[j] * fc2W[j];
#pragma unroll
        for (int o = 32; o > 0; o >>= 1) part += __shfl_down(part, o);
        if (j == 0) consS = part + fc2b[0];
    }
    __syncthreads();
    const float sc = scaleS[lane], sh = shiftS[lane], vd = vdnnS[lane];
    const float C = consS;
#pragma unroll 1
    for (int t = 0; t < 8; ++t) {
        int i = blockIdx.x * 32 + grp * 8 + t;
        float x = H[(size_t)i * 64 + lane] * sc + sh;
        x = fmaxf(x, 0.f) * vd;
#pragma unroll
        for (int o = 32; o > 0; o >>= 1) x += __shfl_down(x, o);
        if (lane == 0) out[i] = x + C;
    }
}

extern "C" void kernel_launch(void* const* d_in, const int* in_sizes, int n_in,
                              void* d_out, int out_size, void* d_ws, size_t ws_size,
                              hipStream_t stream)
{
    const float* x1    = (const float*)d_in[0];
    const float* x2    = (const float*)d_in[1];
    const int*   ei    = (const int*)d_in[2];
    const float* dnnW  = (const float*)d_in[3];
    // d_in[4] = dnn_b: cancels inside BatchNorm, unused
    const float* gamma = (const float*)d_in[5];
    const float* beta  = (const float*)d_in[6];
    const float* g1W   = (const float*)d_in[7];
    const float* g1b   = (const float*)d_in[8];
    const float* g2W   = (const float*)d_in[9];
    const float* g2b   = (const float*)d_in[10];
    const float* fc1W  = (const float*)d_in[11];
    const float* fc1b  = (const float*)d_in[12];
    const float* fc2W  = (const float*)d_in[13];
    const float* fc2b  = (const float*)d_in[14];

    float* ws      = (float*)d_ws;
    ushort* h1h    = (ushort*)ws;                 // 50176*64 ushorts = 1,605,632 f
    float* hdnn    = ws + 1605632;                // 1,048,576 f
    float* dis     = hdnn + 1048576;              // 50,176 f
    int*   cnth    = (int*)(dis + 50176 + 25088); // 50,176 i (keeps old layout)
    uint*  bufC    = (uint*)(cnth + 50176);       // 784*1280 = 1,003,520
    uint*  bufR    = bufC + NBKT * BCAP;          // 1,003,520
    int*   gcurC   = (int*)(bufR + NBKT * BCAP);  // 784   <- zero region start
    int*   gcurR   = gcurC + NBKT;                // 784
    float* bnsum   = (float*)(gcurR + NBKT);      // 64
    float* bnsumsq = bnsum + 64;                  // 64
    float* svec    = bnsumsq + 64;                // 64    <- zero region end (1760)

    zero_kernel<<<1, 256, 0, stream>>>(gcurC, NBKT * 2 + 192);

    mega<<<P1B + DNNB + NBKT, 512, 0, stream>>>(ei, bufC, bufR, gcurC, gcurR,
                                                x1, dnnW, hdnn, bnsum, bnsumsq,
                                                x2, g1W, h1h);
    cnt_dis<<<NBKT, 256, 0, stream>>>(bufC, gcurC, dis, cnth);
    gather_pass<<<NBKT, 512, 0, stream>>>(bufC, gcurC, cnth, bufR, gcurR,
                                          dis, h1h, g1b, svec);
    out_final<<<512, 256, 0, stream>>>(hdnn, bnsum, bnsumsq, gamma, beta, svec,
                                       g2W, g2b, fc1W, fc1b, fc2W, fc2b,
                                       (float*)d_out);
}

// Round 23
// 98.668 us; speedup vs baseline: 1.1932x; 1.0403x over previous
//
#include <hip/hip_runtime.h>
#include <hip/hip_fp16.h>

#define NN 50000
#define NE 800000
#define NB 16384

#define NBKT 784          // buckets of 64 node ids (784*64 = 50176 >= NN)
#define BCAP 1280         // per-bucket capacity (mean 1020, +8 sigma)
#define CAPL 8            // LDS staging depth per bucket per binning block
#define P1B  256          // binning blocks
#define DNNB 256          // DNN gemm blocks (64 rows each)
#define S0   16.0f        // fp8 pre-scale for h1
#define INVS0 0.0625f

typedef unsigned int uint;
typedef unsigned short ushort;
typedef unsigned char uchar;
typedef float floatx2 __attribute__((ext_vector_type(2)));

__device__ __forceinline__ float h2f(ushort u) {
    return __half2float(__ushort_as_half(u));
}

#if defined(__has_builtin)
#if __has_builtin(__builtin_amdgcn_cvt_pk_f32_fp8) && __has_builtin(__builtin_amdgcn_cvt_pk_fp8_f32)
#define HW_FP8 1
#endif
#endif

#ifdef HW_FP8
__device__ __forceinline__ uint enc4fp8(float a, float b, float c, float d) {
    int v = 0;
    v = __builtin_amdgcn_cvt_pk_fp8_f32(a, b, v, false);   // low word
    v = __builtin_amdgcn_cvt_pk_fp8_f32(c, d, v, true);    // high word
    return (uint)v;
}
__device__ __forceinline__ void dec4fp8(uint v, float* o) {
    floatx2 lo = __builtin_amdgcn_cvt_pk_f32_fp8((int)v, false);
    floatx2 hi = __builtin_amdgcn_cvt_pk_f32_fp8((int)v, true);
    o[0] = lo.x; o[1] = lo.y; o[2] = hi.x; o[3] = hi.y;
}
#else
// fallback: manual e4m3fn encode (RNE) / decode
__device__ __forceinline__ uint fp8enc1(float v) {
    uint b = __float_as_uint(v);
    uint s = b >> 31;
    float a = __uint_as_float(b & 0x7fffffffu);
    int Ei = (int)((b >> 23) & 255u) - 127;
    if (Ei < -6) Ei = -6;
    float qinv = __uint_as_float((uint)(130 - Ei) << 23);
    int mt = (int)rintf(a * qinv);
    if (mt >= 16) { mt = 8; Ei += 1; }
    uint e8, m;
    if (mt >= 8) { e8 = (uint)(Ei + 7); m = (uint)(mt - 8); }
    else         { e8 = 0u;             m = (uint)mt; }
    return (s << 7) | (e8 << 3) | m;
}
__device__ __forceinline__ float fp8dec1(uint u) {
    uint e = (u >> 3) & 15u, m = u & 7u;
    float magn = __uint_as_float(((e + 120u) << 23) | (m << 20));
    float mags = (float)m * 0.001953125f;
    float mag = (e != 0u) ? magn : mags;
    return (u & 128u) ? -mag : mag;
}
__device__ __forceinline__ uint enc4fp8(float a, float b, float c, float d) {
    return fp8enc1(a) | (fp8enc1(b) << 8) | (fp8enc1(c) << 16) | (fp8enc1(d) << 24);
}
__device__ __forceinline__ void dec4fp8(uint v, float* o) {
    o[0] = fp8dec1(v & 255u); o[1] = fp8dec1((v >> 8) & 255u);
    o[2] = fp8dec1((v >> 16) & 255u); o[3] = fp8dec1(v >> 24);
}
#endif

// ---------------- zero the counters (runtime fill kernel is pathological) ------
__global__ void zero_kernel(int* __restrict__ p, int n)
{
    for (int i = threadIdx.x; i < n; i += 256) p[i] = 0;
}

// ---------------- megakernel: bin (2-pass) + DNN GEMM(+BN) + GCN GEMM ----------
// Blocks [0,256): binning ; [256,512): DNN ; [512,1296): GCN1 (fp8 out).
struct BinSh {
    uint st[NBKT * CAPL];                       // 25 KiB
    int lc[NBKT];                               // 3.1 KiB
};
union MegaSh {
    BinSh b;                                    // 28.2 KiB
    float xs[64 * 65];                          // 16.6 KiB (GEMM branches)
};

__global__ __launch_bounds__(512) void mega(const int* __restrict__ ei,
    uint* __restrict__ bufC, uint* __restrict__ bufR,
    int* __restrict__ gcurC, int* __restrict__ gcurR,
    const float* __restrict__ X1, const float* __restrict__ Wd,
    float* __restrict__ H, float* __restrict__ bnsum,
    float* __restrict__ bnsumsq,
    const float* __restrict__ X2, const float* __restrict__ W1,
    uchar* __restrict__ h8)
{
    __shared__ MegaSh sh;
    const int tid = threadIdx.x;
    const int lane = tid & 63;
    const int wv = __builtin_amdgcn_readfirstlane(tid >> 6);   // 0..7

    if (blockIdx.x < P1B) {
        BinSh& B = sh.b;
        const int per = (NE + P1B - 1) / P1B;
        const int lo = blockIdx.x * per;
        const int hi = (lo + per < NE) ? lo + per : NE;
        // ---- pass 1: bin by col>>6, ent = (r<<6)|(c&63) ----
        for (int i = tid; i < NBKT; i += 512) B.lc[i] = 0;
        __syncthreads();
        for (int e = lo + tid; e < hi; e += 512) {
            int r = ei[e], c = ei[NE + e];
            uint ent = ((uint)r << 6) | (uint)(c & 63);
            int b = c >> 6;
            int pos = atomicAdd(&B.lc[b], 1);
            if (pos < CAPL) B.st[b * CAPL + pos] = ent;
            else { int gp = atomicAdd(&gcurC[b], 1); bufC[(size_t)b * BCAP + gp] = ent; }
        }
        __syncthreads();
        for (int base = wv * 8; base < NBKT; base += 64) {
            int wb = base + (lane >> 3);
            int idx = lane & 7;
            int n = B.lc[wb]; if (n > CAPL) n = CAPL;
            int gb = 0;
            if (idx == 0 && n > 0) gb = atomicAdd(&gcurC[wb], n);
            gb = __shfl(gb, lane & 56);
            if (idx < n) bufC[(size_t)wb * BCAP + gb + idx] = B.st[wb * CAPL + idx];
        }
        __syncthreads();
        // ---- pass 2: bin by row>>6, ent = ((r&63)<<16)|c ----
        for (int i = tid; i < NBKT; i += 512) B.lc[i] = 0;
        __syncthreads();
        for (int e = lo + tid; e < hi; e += 512) {
            int r = ei[e], c = ei[NE + e];
            uint ent = ((uint)(r & 63) << 16) | (uint)c;
            int rb = r >> 6;
            int pos = atomicAdd(&B.lc[rb], 1);
            if (pos < CAPL) B.st[rb * CAPL + pos] = ent;
            else { int gp = atomicAdd(&gcurR[rb], 1); bufR[(size_t)rb * BCAP + gp] = ent; }
        }
        __syncthreads();
        for (int base = wv * 8; base < NBKT; base += 64) {
            int wb = base + (lane >> 3);
            int idx = lane & 7;
            int n = B.lc[wb]; if (n > CAPL) n = CAPL;
            int gb = 0;
            if (idx == 0 && n > 0) gb = atomicAdd(&gcurR[wb], n);
            gb = __shfl(gb, lane & 56);
            if (idx < n) bufR[(size_t)wb * BCAP + gb + idx] = B.st[wb * CAPL + idx];
        }
        return;
    }

    if (blockIdx.x < P1B + DNNB) {
        // ---- DNN: 64 rows, K=256 in 4 staged chunks, lane = row, 8 waves ----
        float* xs = sh.xs;
        const int c0 = wv * 8;
        const int row0 = (blockIdx.x - P1B) * 64;
        float acc[8];
#pragma unroll
        for (int j = 0; j < 8; ++j) acc[j] = 0.f;
#pragma unroll 1
        for (int chunk = 0; chunk < 4; ++chunk) {
            if (chunk) __syncthreads();
            for (int i = tid; i < 4096; i += 512) {
                int r = i >> 6, k = i & 63;
                xs[r * 65 + k] = X1[(size_t)(row0 + r) * 256 + chunk * 64 + k];
            }
            __syncthreads();
            const float* xrow = xs + lane * 65;
#pragma unroll
            for (int k4 = 0; k4 < 16; ++k4) {
                float x0 = xrow[4 * k4 + 0];
                float x1 = xrow[4 * k4 + 1];
                float x2 = xrow[4 * k4 + 2];
                float x3 = xrow[4 * k4 + 3];
                const float* wr = Wd + (size_t)(chunk * 64 + 4 * k4) * 64 + c0;
#pragma unroll
                for (int j = 0; j < 8; ++j) {
                    float a = acc[j];
                    a = fmaf(x0, wr[j],       a);
                    a = fmaf(x1, wr[64 + j],  a);
                    a = fmaf(x2, wr[128 + j], a);
                    a = fmaf(x3, wr[192 + j], a);
                    acc[j] = a;
                }
            }
        }
        __syncthreads();
#pragma unroll
        for (int j = 0; j < 8; ++j) xs[lane * 65 + c0 + j] = acc[j];
        __syncthreads();
        float s = 0.f, q = 0.f;
        for (int i = tid; i < 4096; i += 512) {
            int r = i >> 6, c = i & 63;
            float v = xs[r * 65 + c];
            H[(size_t)(row0 + r) * 64 + c] = v;
            s += v; q += v * v;
        }
        __syncthreads();
        float* red = xs;
        red[tid] = s; red[512 + tid] = q;
        __syncthreads();
        if (tid < 64) {
            float ss = 0.f, qq = 0.f;
#pragma unroll
            for (int gidx = 0; gidx < 8; ++gidx) {
                ss += red[gidx * 64 + tid];
                qq += red[512 + gidx * 64 + tid];
            }
            atomicAdd(&bnsum[tid], ss);
            atomicAdd(&bnsumsq[tid], qq);
        }
        return;
    }

    // ---- GCN1: h8 = fp8(S0 * (x2 @ g1W)) UNSCALED-by-dis, K=64, 8 waves ----
    {
        float* xs = sh.xs;
        const int c0 = wv * 8;
        const int row0 = (blockIdx.x - P1B - DNNB) * 64;
        float acc[8];
#pragma unroll
        for (int j = 0; j < 8; ++j) acc[j] = 0.f;
        if (row0 + 64 <= NN) {
            for (int i = tid; i < 4096; i += 512) {
                int r = i >> 6, k = i & 63;
                xs[r * 65 + k] = X2[(size_t)(row0 + r) * 64 + k];
            }
        } else {
            for (int i = tid; i < 4096; i += 512) {
                int r = i >> 6, k = i & 63;
                xs[r * 65 + k] = (row0 + r < NN)
                               ? X2[(size_t)(row0 + r) * 64 + k] : 0.f;
            }
        }
        __syncthreads();
        const float* xrow = xs + lane * 65;
#pragma unroll
        for (int k4 = 0; k4 < 16; ++k4) {
            float x0 = xrow[4 * k4 + 0];
            float x1 = xrow[4 * k4 + 1];
            float x2 = xrow[4 * k4 + 2];
            float x3 = xrow[4 * k4 + 3];
            const float* wr = W1 + (size_t)(4 * k4) * 64 + c0;
#pragma unroll
            for (int j = 0; j < 8; ++j) {
                float a = acc[j];
                a = fmaf(x0, wr[j],       a);
                a = fmaf(x1, wr[64 + j],  a);
                a = fmaf(x2, wr[128 + j], a);
                a = fmaf(x3, wr[192 + j], a);
                acc[j] = a;
            }
        }
        __syncthreads();
#pragma unroll
        for (int j = 0; j < 8; ++j) xs[lane * 65 + c0 + j] = S0 * acc[j];
        __syncthreads();
        // coalesced fp8 store: tid-linear over 64 rows x 16 uint quads
        for (int i = tid; i < 1024; i += 512) {
            int r = i >> 4, c4 = (i & 15) << 2;
            int row = row0 + r;
            if (row < NN) {
                const float* xr4 = xs + r * 65 + c4;
                uint v = enc4fp8(xr4[0], xr4[1], xr4[2], xr4[3]);
                *reinterpret_cast<uint*>(h8 + (size_t)row * 64 + c4) = v;
            }
        }
    }
}

// ---------------- per-bucket in-degree histogram -> dis, cnth ------------------
__global__ __launch_bounds__(256) void cnt_dis(const uint* __restrict__ bufC,
    const int* __restrict__ gcurC, float* __restrict__ dis,
    int* __restrict__ cnth)
{
    __shared__ int hist[64];
    const int tid = threadIdx.x, bb = blockIdx.x;
    if (tid < 64) hist[tid] = 0;
    __syncthreads();
    const int n = gcurC[bb];
    const uint* src = bufC + (size_t)bb * BCAP;
    for (int i = tid; i < n; i += 256) atomicAdd(&hist[src[i] & 63], 1);
    __syncthreads();
    if (tid < 64) {
        int c = bb * 64 + tid;
        cnth[bb * 64 + tid] = hist[tid];
        if (c < NN) dis[c] = rsqrtf((float)hist[tid] + 1.0f);
    }
}

// ---------------- gather (fp8 rows, HW decode, per-edge dis) -------------------
// acc8 = sum_in dis_r*h8_r ; g_c = (dis_c/S0)*(acc8 + dis_c*h8_c) + b1 ;
// coef_c = dis_c*w_c + dis_c^2
__global__ __launch_bounds__(512) void gather_pass(const uint* __restrict__ bufC,
    const int* __restrict__ gcurC, const int* __restrict__ cnth,
    const uint* __restrict__ bufR, const int* __restrict__ gcurR,
    const float* __restrict__ dis, const uchar* __restrict__ h8,
    const float* __restrict__ b1, float* __restrict__ svec)
{
    __shared__ int sorted[BCAP];
    __shared__ int cntS[64], offsS[64], curS[64];
    __shared__ float w[64], disS[64];
    __shared__ float red[8][64];
    const int tid = threadIdx.x;
    const int lane = tid & 63;
    const int wv = __builtin_amdgcn_readfirstlane(tid >> 6);   // 0..7
    const int bb = blockIdx.x;
    const int g4 = lane >> 4;                    // edge sub-group 0..3
    const int l16 = lane & 15;                   // col-quad index
    if (tid < 64) {                              // wave 0: load hist + scan + dis
        w[tid] = 0.f;
        int v = cnth[bb * 64 + tid];
        cntS[tid] = v;
        disS[tid] = rsqrtf((float)v + 1.0f);
        int s = v;
#pragma unroll
        for (int o = 1; o < 64; o <<= 1) {
            int u = __shfl_up(s, o);
            if (lane >= o) s += u;
        }
        offsS[tid] = s - v;
        curS[tid] = s - v;
    }
    __syncthreads();
    // wraw accumulation from the row-bucket (dis is a 200 KB L2-resident table)
    const int n2 = gcurR[bb];
    const uint* srcR = bufR + (size_t)bb * BCAP;
    for (int i = tid; i < n2; i += 512) {
        uint e = srcR[i];
        atomicAdd(&w[e >> 16], dis[e & 0xffffu]);
    }
    // LDS counting-sort scatter of the col-bucket
    const int n = gcurC[bb];
    const uint* src = bufC + (size_t)bb * BCAP;
    for (int i = tid; i < n; i += 512) {
        uint e = src[i];
        int p = atomicAdd(&curS[e & 63u], 1);
        sorted[p] = (int)(e >> 6);
    }
    __syncthreads();
    // each wave: 8 consecutive nodes; 8 edges/iter, uint (4 fp8 cols)/lane
    float sacc0 = 0.f, sacc1 = 0.f, sacc2 = 0.f, sacc3 = 0.f;
    const float4 blv = *reinterpret_cast<const float4*>(b1 + (l16 << 2));
#pragma unroll 1
    for (int t = 0; t < 8; ++t) {
        const int nd = wv * 8 + t;
        const int lo = offsS[nd], hi2 = lo + cntS[nd];
        float a0 = 0.f, a1 = 0.f, a2 = 0.f, a3 = 0.f;
        for (int e = lo; e < hi2; e += 8) {
            int i0 = e + g4;
            int i1 = e + 4 + g4;
            int j0 = (i0 < hi2) ? i0 : hi2 - 1;
            int j1 = (i1 < hi2) ? i1 : hi2 - 1;
            float m0 = (i0 < hi2) ? 1.f : 0.f;
            float m1 = (i1 < hi2) ? 1.f : 0.f;
            int r0 = sorted[j0];
            int r1 = sorted[j1];
            float sd0 = m0 * dis[r0];            // broadcast 4B load
            float sd1 = m1 * dis[r1];
            uint v0 = *reinterpret_cast<const uint*>(h8 + ((size_t)r0 << 6) + (l16 << 2));
            uint v1 = *reinterpret_cast<const uint*>(h8 + ((size_t)r1 << 6) + (l16 << 2));
            float f0[4], f1[4];
            dec4fp8(v0, f0);
            dec4fp8(v1, f1);
            a0 = fmaf(sd0, f0[0], a0);
            a1 = fmaf(sd0, f0[1], a1);
            a2 = fmaf(sd0, f0[2], a2);
            a3 = fmaf(sd0, f0[3], a3);
            a0 = fmaf(sd1, f1[0], a0);
            a1 = fmaf(sd1, f1[1], a1);
            a2 = fmaf(sd1, f1[2], a2);
            a3 = fmaf(sd1, f1[3], a3);
        }
        // combine the 4 edge sub-groups
        a0 += __shfl_xor(a0, 16); a0 += __shfl_xor(a0, 32);
        a1 += __shfl_xor(a1, 16); a1 += __shfl_xor(a1, 32);
        a2 += __shfl_xor(a2, 16); a2 += __shfl_xor(a2, 32);
        a3 += __shfl_xor(a3, 16); a3 += __shfl_xor(a3, 32);
        const int c = bb * 64 + nd;
        if (c < NN) {
            float d = disS[nd];
            float dS = d * INVS0;
            float coef = fmaf(d, w[nd], d * d);
            uint sv = *reinterpret_cast<const uint*>(h8 + ((size_t)c << 6) + (l16 << 2));
            float fc[4];
            dec4fp8(sv, fc);
            float g0 = fmaf(dS, fmaf(d, fc[0], a0), blv.x);
            float g1 = fmaf(dS, fmaf(d, fc[1], a1), blv.y);
            float g2 = fmaf(dS, fmaf(d, fc[2], a2), blv.z);
            float g3 = fmaf(dS, fmaf(d, fc[3], a3), blv.w);
            sacc0 = fmaf(coef, fmaxf(g0, 0.f), sacc0);
            sacc1 = fmaf(coef, fmaxf(g1, 0.f), sacc1);
            sacc2 = fmaf(coef, fmaxf(g2, 0.f), sacc2);
            sacc3 = fmaf(coef, fmaxf(g3, 0.f), sacc3);
        }
    }
    if (g4 == 0) {
        red[wv][(l16 << 2) + 0] = sacc0;
        red[wv][(l16 << 2) + 1] = sacc1;
        red[wv][(l16 << 2) + 2] = sacc2;
        red[wv][(l16 << 2) + 3] = sacc3;
    }
    __syncthreads();
    if (wv == 0) {
        float s = ((red[0][lane] + red[1][lane]) + (red[2][lane] + red[3][lane])) +
                  ((red[4][lane] + red[5][lane]) + (red[6][lane] + red[7][lane]));
        atomicAdd(&svec[lane], s);
    }
}

// ---------------- output + fused finalize --------------------------------------
__global__ __launch_bounds__(256) void out_final(const float* __restrict__ H,
    const float* __restrict__ bnsum, const float* __restrict__ bnsumsq,
    const float* __restrict__ gamma, const float* __restrict__ beta,
    const float* __restrict__ svec, const float* __restrict__ g2W,
    const float* __restrict__ g2b, const float* __restrict__ fc1W,
    const float* __restrict__ fc1b, const float* __restrict__ fc2W,
    const float* __restrict__ fc2b, float* __restrict__ out)
{
    __shared__ float scaleS[64], shiftS[64], vdnnS[64];
    __shared__ float consS;
    const int tid = threadIdx.x;
    const int lane = tid & 63;
    const int grp = tid >> 6;
    if (tid < 64) {                              // wave 0 computes finalize
        int j = tid;
        float mu = bnsum[j] * (1.0f / NB);
        float var = bnsumsq[j] * (1.0f / NB) - mu * mu;
        float sc = rsqrtf(var + 1e-5f) * gamma[j];
        scaleS[j] = sc;
        shiftS[j] = beta[j] - mu * sc;
        float ge = 0.f;
        for (int k = 0; k < 64; ++k) ge += svec[k] * g2W[k * 64 + j];
        ge = ge * (1.0f / NN) + g2b[j];
        float vd = 0.f, vg = 0.f;
        for (int k = 0; k < 64; ++k) {
            vd += fc1W[j * 64 + k] * fc2W[k];
            vg += fc1W[(64 + j) * 64 + k] * fc2W[k];
        }
        vdnnS[j] = vd;
        float part = ge * vg + fc1b[j] * fc2W[j];
#pragma unroll
        for (int o = 32; o > 0; o >>= 1) part += __shfl_down(part, o);
        if (j == 0) consS = part + fc2b[0];
    }
    __syncthreads();
    const float sc = scaleS[lane], sh = shiftS[lane], vd = vdnnS[lane];
    const float C = consS;
#pragma unroll 1
    for (int t = 0; t < 8; ++t) {
        int i = blockIdx.x * 32 + grp * 8 + t;
        float x = H[(size_t)i * 64 + lane] * sc + sh;
        x = fmaxf(x, 0.f) * vd;
#pragma unroll
        for (int o = 32; o > 0; o >>= 1) x += __shfl_down(x, o);
        if (lane == 0) out[i] = x + C;
    }
}

extern "C" void kernel_launch(void* const* d_in, const int* in_sizes, int n_in,
                              void* d_out, int out_size, void* d_ws, size_t ws_size,
                              hipStream_t stream)
{
    const float* x1    = (const float*)d_in[0];
    const float* x2    = (const float*)d_in[1];
    const int*   ei    = (const int*)d_in[2];
    const float* dnnW  = (const float*)d_in[3];
    // d_in[4] = dnn_b: cancels inside BatchNorm, unused
    const float* gamma = (const float*)d_in[5];
    const float* beta  = (const float*)d_in[6];
    const float* g1W   = (const float*)d_in[7];
    const float* g1b   = (const float*)d_in[8];
    const float* g2W   = (const float*)d_in[9];
    const float* g2b   = (const float*)d_in[10];
    const float* fc1W  = (const float*)d_in[11];
    const float* fc1b  = (const float*)d_in[12];
    const float* fc2W  = (const float*)d_in[13];
    const float* fc2b  = (const float*)d_in[14];

    float* ws      = (float*)d_ws;
    uchar* h8      = (uchar*)ws;                  // 50176*64 B = 802,816 floats
    float* hdnn    = ws + 1605632;                // 1,048,576 f (layout kept)
    float* dis     = hdnn + 1048576;              // 50,176 f
    int*   cnth    = (int*)(dis + 50176 + 25088); // 50,176 i
    uint*  bufC    = (uint*)(cnth + 50176);       // 784*1280 = 1,003,520
    uint*  bufR    = bufC + NBKT * BCAP;          // 1,003,520
    int*   gcurC   = (int*)(bufR + NBKT * BCAP);  // 784   <- zero region start
    int*   gcurR   = gcurC + NBKT;                // 784
    float* bnsum   = (float*)(gcurR + NBKT);      // 64
    float* bnsumsq = bnsum + 64;                  // 64
    float* svec    = bnsumsq + 64;                // 64    <- zero region end (1760)

    zero_kernel<<<1, 256, 0, stream>>>(gcurC, NBKT * 2 + 192);

    mega<<<P1B + DNNB + NBKT, 512, 0, stream>>>(ei, bufC, bufR, gcurC, gcurR,
                                                x1, dnnW, hdnn, bnsum, bnsumsq,
                                                x2, g1W, h8);
    cnt_dis<<<NBKT, 256, 0, stream>>>(bufC, gcurC, dis, cnth);
    gather_pass<<<NBKT, 512, 0, stream>>>(bufC, gcurC, cnth, bufR, gcurR,
                                          dis, h8, g1b, svec);
    out_final<<<512, 256, 0, stream>>>(hdnn, bnsum, bnsumsq, gamma, beta, svec,
                                       g2W, g2b, fc1W, fc1b, fc2W, fc2b,
                                       (float*)d_out);
}

// Round 24
// 88.671 us; speedup vs baseline: 1.3277x; 1.1127x over previous
//
#include <hip/hip_runtime.h>
#include <hip/hip_fp16.h>

#define NN 50000
#define NE 800000
#define NB 16384

#define NBKT 784          // buckets of 64 node ids (784*64 = 50176 >= NN)
#define BCAP 1280         // per-bucket capacity (mean 1020, +8 sigma)
#define CAPL 16           // LDS staging depth per bucket per binning block
#define P1B  128          // binning blocks (mean 8 entries/bucket/block/pass)
#define DNNB 256          // DNN gemm blocks (64 rows each)
#define S0   16.0f        // fp8 pre-scale for h1
#define INVS0 0.0625f

typedef unsigned int uint;
typedef unsigned short ushort;
typedef unsigned char uchar;
typedef float floatx2 __attribute__((ext_vector_type(2)));

__device__ __forceinline__ float h2f(ushort u) {
    return __half2float(__ushort_as_half(u));
}

#if defined(__has_builtin)
#if __has_builtin(__builtin_amdgcn_cvt_pk_f32_fp8) && __has_builtin(__builtin_amdgcn_cvt_pk_fp8_f32)
#define HW_FP8 1
#endif
#endif

#ifdef HW_FP8
__device__ __forceinline__ uint enc4fp8(float a, float b, float c, float d) {
    int v = 0;
    v = __builtin_amdgcn_cvt_pk_fp8_f32(a, b, v, false);   // low word
    v = __builtin_amdgcn_cvt_pk_fp8_f32(c, d, v, true);    // high word
    return (uint)v;
}
__device__ __forceinline__ void dec4fp8(uint v, float* o) {
    floatx2 lo = __builtin_amdgcn_cvt_pk_f32_fp8((int)v, false);
    floatx2 hi = __builtin_amdgcn_cvt_pk_f32_fp8((int)v, true);
    o[0] = lo.x; o[1] = lo.y; o[2] = hi.x; o[3] = hi.y;
}
#else
// fallback: manual e4m3fn encode (RNE) / decode
__device__ __forceinline__ uint fp8enc1(float v) {
    uint b = __float_as_uint(v);
    uint s = b >> 31;
    float a = __uint_as_float(b & 0x7fffffffu);
    int Ei = (int)((b >> 23) & 255u) - 127;
    if (Ei < -6) Ei = -6;
    float qinv = __uint_as_float((uint)(130 - Ei) << 23);
    int mt = (int)rintf(a * qinv);
    if (mt >= 16) { mt = 8; Ei += 1; }
    uint e8, m;
    if (mt >= 8) { e8 = (uint)(Ei + 7); m = (uint)(mt - 8); }
    else         { e8 = 0u;             m = (uint)mt; }
    return (s << 7) | (e8 << 3) | m;
}
__device__ __forceinline__ float fp8dec1(uint u) {
    uint e = (u >> 3) & 15u, m = u & 7u;
    float magn = __uint_as_float(((e + 120u) << 23) | (m << 20));
    float mags = (float)m * 0.001953125f;
    float mag = (e != 0u) ? magn : mags;
    return (u & 128u) ? -mag : mag;
}
__device__ __forceinline__ uint enc4fp8(float a, float b, float c, float d) {
    return fp8enc1(a) | (fp8enc1(b) << 8) | (fp8enc1(c) << 16) | (fp8enc1(d) << 24);
}
__device__ __forceinline__ void dec4fp8(uint v, float* o) {
    o[0] = fp8dec1(v & 255u); o[1] = fp8dec1((v >> 8) & 255u);
    o[2] = fp8dec1((v >> 16) & 255u); o[3] = fp8dec1(v >> 24);
}
#endif

// ---------------- zero the counters (runtime fill kernel is pathological) ------
__global__ void zero_kernel(int* __restrict__ p, int n)
{
    for (int i = threadIdx.x; i < n; i += 256) p[i] = 0;
}

// ---------------- megakernel: bin (2-pass) + DNN GEMM(+BN) + GCN GEMM ----------
// Blocks [0,128): binning ; [128,384): DNN ; [384,1168): GCN1 (fp8 out).
struct BinSh {
    uint st[NBKT * CAPL];                       // 50 KiB
    int lc[NBKT];                               // 3.1 KiB
};
union MegaSh {
    BinSh b;                                    // 53.3 KiB
    float xs[64 * 65];                          // 16.6 KiB (GEMM branches)
};

__global__ __launch_bounds__(512) void mega(const int* __restrict__ ei,
    uint* __restrict__ bufC, uint* __restrict__ bufR,
    int* __restrict__ gcurC, int* __restrict__ gcurR,
    const float* __restrict__ X1, const float* __restrict__ Wd,
    float* __restrict__ H, float* __restrict__ bnsum,
    float* __restrict__ bnsumsq,
    const float* __restrict__ X2, const float* __restrict__ W1,
    uchar* __restrict__ h8)
{
    __shared__ MegaSh sh;
    const int tid = threadIdx.x;
    const int lane = tid & 63;
    const int wv = __builtin_amdgcn_readfirstlane(tid >> 6);   // 0..7

    if (blockIdx.x < P1B) {
        BinSh& B = sh.b;
        const int per = (NE + P1B - 1) / P1B;
        const int lo = blockIdx.x * per;
        const int hi = (lo + per < NE) ? lo + per : NE;
        // ---- pass 1: bin by col>>6, ent = (r<<6)|(c&63) ----
        for (int i = tid; i < NBKT; i += 512) B.lc[i] = 0;
        __syncthreads();
        for (int e = lo + tid; e < hi; e += 512) {
            int r = ei[e], c = ei[NE + e];
            uint ent = ((uint)r << 6) | (uint)(c & 63);
            int b = c >> 6;
            int pos = atomicAdd(&B.lc[b], 1);
            if (pos < CAPL) B.st[b * CAPL + pos] = ent;
            else { int gp = atomicAdd(&gcurC[b], 1); bufC[(size_t)b * BCAP + gp] = ent; }
        }
        __syncthreads();
        // flush: 8 buckets/wave-iter, 8 lanes/bucket, 2 entries/lane
        for (int base = wv * 8; base < NBKT; base += 64) {
            int wb = base + (lane >> 3);
            int idx = lane & 7;
            int n = B.lc[wb]; if (n > CAPL) n = CAPL;
            int gb = 0;
            if (idx == 0 && n > 0) gb = atomicAdd(&gcurC[wb], n);
            gb = __shfl(gb, lane & 56);
            if (idx < n) bufC[(size_t)wb * BCAP + gb + idx] = B.st[wb * CAPL + idx];
            if (idx + 8 < n) bufC[(size_t)wb * BCAP + gb + idx + 8] = B.st[wb * CAPL + idx + 8];
        }
        __syncthreads();
        // ---- pass 2: bin by row>>6, ent = ((r&63)<<16)|c ----
        for (int i = tid; i < NBKT; i += 512) B.lc[i] = 0;
        __syncthreads();
        for (int e = lo + tid; e < hi; e += 512) {
            int r = ei[e], c = ei[NE + e];
            uint ent = ((uint)(r & 63) << 16) | (uint)c;
            int rb = r >> 6;
            int pos = atomicAdd(&B.lc[rb], 1);
            if (pos < CAPL) B.st[rb * CAPL + pos] = ent;
            else { int gp = atomicAdd(&gcurR[rb], 1); bufR[(size_t)rb * BCAP + gp] = ent; }
        }
        __syncthreads();
        for (int base = wv * 8; base < NBKT; base += 64) {
            int wb = base + (lane >> 3);
            int idx = lane & 7;
            int n = B.lc[wb]; if (n > CAPL) n = CAPL;
            int gb = 0;
            if (idx == 0 && n > 0) gb = atomicAdd(&gcurR[wb], n);
            gb = __shfl(gb, lane & 56);
            if (idx < n) bufR[(size_t)wb * BCAP + gb + idx] = B.st[wb * CAPL + idx];
            if (idx + 8 < n) bufR[(size_t)wb * BCAP + gb + idx + 8] = B.st[wb * CAPL + idx + 8];
        }
        return;
    }

    if (blockIdx.x < P1B + DNNB) {
        // ---- DNN: 64 rows, K=256 in 4 staged chunks, lane = row, 8 waves ----
        float* xs = sh.xs;
        const int c0 = wv * 8;
        const int row0 = (blockIdx.x - P1B) * 64;
        float acc[8];
#pragma unroll
        for (int j = 0; j < 8; ++j) acc[j] = 0.f;
#pragma unroll 1
        for (int chunk = 0; chunk < 4; ++chunk) {
            if (chunk) __syncthreads();
            for (int i = tid; i < 4096; i += 512) {
                int r = i >> 6, k = i & 63;
                xs[r * 65 + k] = X1[(size_t)(row0 + r) * 256 + chunk * 64 + k];
            }
            __syncthreads();
            const float* xrow = xs + lane * 65;
#pragma unroll
            for (int k4 = 0; k4 < 16; ++k4) {
                float x0 = xrow[4 * k4 + 0];
                float x1 = xrow[4 * k4 + 1];
                float x2 = xrow[4 * k4 + 2];
                float x3 = xrow[4 * k4 + 3];
                const float* wr = Wd + (size_t)(chunk * 64 + 4 * k4) * 64 + c0;
#pragma unroll
                for (int j = 0; j < 8; ++j) {
                    float a = acc[j];
                    a = fmaf(x0, wr[j],       a);
                    a = fmaf(x1, wr[64 + j],  a);
                    a = fmaf(x2, wr[128 + j], a);
                    a = fmaf(x3, wr[192 + j], a);
                    acc[j] = a;
                }
            }
        }
        __syncthreads();
#pragma unroll
        for (int j = 0; j < 8; ++j) xs[lane * 65 + c0 + j] = acc[j];
        __syncthreads();
        float s = 0.f, q = 0.f;
        for (int i = tid; i < 4096; i += 512) {
            int r = i >> 6, c = i & 63;
            float v = xs[r * 65 + c];
            H[(size_t)(row0 + r) * 64 + c] = v;
            s += v; q += v * v;
        }
        __syncthreads();
        float* red = xs;
        red[tid] = s; red[512 + tid] = q;
        __syncthreads();
        if (tid < 64) {
            float ss = 0.f, qq = 0.f;
#pragma unroll
            for (int gidx = 0; gidx < 8; ++gidx) {
                ss += red[gidx * 64 + tid];
                qq += red[512 + gidx * 64 + tid];
            }
            atomicAdd(&bnsum[tid], ss);
            atomicAdd(&bnsumsq[tid], qq);
        }
        return;
    }

    // ---- GCN1: h8 = fp8(S0 * (x2 @ g1W)) UNSCALED-by-dis, K=64, 8 waves ----
    {
        float* xs = sh.xs;
        const int c0 = wv * 8;
        const int row0 = (blockIdx.x - P1B - DNNB) * 64;
        float acc[8];
#pragma unroll
        for (int j = 0; j < 8; ++j) acc[j] = 0.f;
        if (row0 + 64 <= NN) {
            for (int i = tid; i < 4096; i += 512) {
                int r = i >> 6, k = i & 63;
                xs[r * 65 + k] = X2[(size_t)(row0 + r) * 64 + k];
            }
        } else {
            for (int i = tid; i < 4096; i += 512) {
                int r = i >> 6, k = i & 63;
                xs[r * 65 + k] = (row0 + r < NN)
                               ? X2[(size_t)(row0 + r) * 64 + k] : 0.f;
            }
        }
        __syncthreads();
        const float* xrow = xs + lane * 65;
#pragma unroll
        for (int k4 = 0; k4 < 16; ++k4) {
            float x0 = xrow[4 * k4 + 0];
            float x1 = xrow[4 * k4 + 1];
            float x2 = xrow[4 * k4 + 2];
            float x3 = xrow[4 * k4 + 3];
            const float* wr = W1 + (size_t)(4 * k4) * 64 + c0;
#pragma unroll
            for (int j = 0; j < 8; ++j) {
                float a = acc[j];
                a = fmaf(x0, wr[j],       a);
                a = fmaf(x1, wr[64 + j],  a);
                a = fmaf(x2, wr[128 + j], a);
                a = fmaf(x3, wr[192 + j], a);
                acc[j] = a;
            }
        }
        __syncthreads();
#pragma unroll
        for (int j = 0; j < 8; ++j) xs[lane * 65 + c0 + j] = S0 * acc[j];
        __syncthreads();
        // coalesced fp8 store: tid-linear over 64 rows x 16 uint quads
        for (int i = tid; i < 1024; i += 512) {
            int r = i >> 4, c4 = (i & 15) << 2;
            int row = row0 + r;
            if (row < NN) {
                const float* xr4 = xs + r * 65 + c4;
                uint v = enc4fp8(xr4[0], xr4[1], xr4[2], xr4[3]);
                *reinterpret_cast<uint*>(h8 + (size_t)row * 64 + c4) = v;
            }
        }
    }
}

// ---------------- per-bucket in-degree histogram -> dis, cnth ------------------
__global__ __launch_bounds__(256) void cnt_dis(const uint* __restrict__ bufC,
    const int* __restrict__ gcurC, float* __restrict__ dis,
    int* __restrict__ cnth)
{
    __shared__ int hist[64];
    const int tid = threadIdx.x, bb = blockIdx.x;
    if (tid < 64) hist[tid] = 0;
    __syncthreads();
    const int n = gcurC[bb];
    const uint* src = bufC + (size_t)bb * BCAP;
    for (int i = tid; i < n; i += 256) atomicAdd(&hist[src[i] & 63], 1);
    __syncthreads();
    if (tid < 64) {
        int c = bb * 64 + tid;
        cnth[bb * 64 + tid] = hist[tid];
        if (c < NN) dis[c] = rsqrtf((float)hist[tid] + 1.0f);
    }
}

// ---------------- gather (fp8 rows, HW decode, per-edge dis) -------------------
// acc8 = sum_in dis_r*h8_r ; g_c = (dis_c/S0)*(acc8 + dis_c*h8_c) + b1 ;
// coef_c = dis_c*w_c + dis_c^2
__global__ __launch_bounds__(512) void gather_pass(const uint* __restrict__ bufC,
    const int* __restrict__ gcurC, const int* __restrict__ cnth,
    const uint* __restrict__ bufR, const int* __restrict__ gcurR,
    const float* __restrict__ dis, const uchar* __restrict__ h8,
    const float* __restrict__ b1, float* __restrict__ svec)
{
    __shared__ int sorted[BCAP];
    __shared__ int cntS[64], offsS[64], curS[64];
    __shared__ float w[64], disS[64];
    __shared__ float red[8][64];
    const int tid = threadIdx.x;
    const int lane = tid & 63;
    const int wv = __builtin_amdgcn_readfirstlane(tid >> 6);   // 0..7
    const int bb = blockIdx.x;
    const int g4 = lane >> 4;                    // edge sub-group 0..3
    const int l16 = lane & 15;                   // col-quad index
    if (tid < 64) {                              // wave 0: load hist + scan + dis
        w[tid] = 0.f;
        int v = cnth[bb * 64 + tid];
        cntS[tid] = v;
        disS[tid] = rsqrtf((float)v + 1.0f);
        int s = v;
#pragma unroll
        for (int o = 1; o < 64; o <<= 1) {
            int u = __shfl_up(s, o);
            if (lane >= o) s += u;
        }
        offsS[tid] = s - v;
        curS[tid] = s - v;
    }
    __syncthreads();
    // wraw accumulation from the row-bucket (dis is a 200 KB L2-resident table)
    const int n2 = gcurR[bb];
    const uint* srcR = bufR + (size_t)bb * BCAP;
    for (int i = tid; i < n2; i += 512) {
        uint e = srcR[i];
        atomicAdd(&w[e >> 16], dis[e & 0xffffu]);
    }
    // LDS counting-sort scatter of the col-bucket
    const int n = gcurC[bb];
    const uint* src = bufC + (size_t)bb * BCAP;
    for (int i = tid; i < n; i += 512) {
        uint e = src[i];
        int p = atomicAdd(&curS[e & 63u], 1);
        sorted[p] = (int)(e >> 6);
    }
    __syncthreads();
    // each wave: 8 consecutive nodes; 8 edges/iter, uint (4 fp8 cols)/lane
    float sacc0 = 0.f, sacc1 = 0.f, sacc2 = 0.f, sacc3 = 0.f;
    const float4 blv = *reinterpret_cast<const float4*>(b1 + (l16 << 2));
#pragma unroll 1
    for (int t = 0; t < 8; ++t) {
        const int nd = wv * 8 + t;
        const int lo = offsS[nd], hi2 = lo + cntS[nd];
        float a0 = 0.f, a1 = 0.f, a2 = 0.f, a3 = 0.f;
        for (int e = lo; e < hi2; e += 8) {
            int i0 = e + g4;
            int i1 = e + 4 + g4;
            int j0 = (i0 < hi2) ? i0 : hi2 - 1;
            int j1 = (i1 < hi2) ? i1 : hi2 - 1;
            float m0 = (i0 < hi2) ? 1.f : 0.f;
            float m1 = (i1 < hi2) ? 1.f : 0.f;
            int r0 = sorted[j0];
            int r1 = sorted[j1];
            float sd0 = m0 * dis[r0];            // broadcast 4B load
            float sd1 = m1 * dis[r1];
            uint v0 = *reinterpret_cast<const uint*>(h8 + ((size_t)r0 << 6) + (l16 << 2));
            uint v1 = *reinterpret_cast<const uint*>(h8 + ((size_t)r1 << 6) + (l16 << 2));
            float f0[4], f1[4];
            dec4fp8(v0, f0);
            dec4fp8(v1, f1);
            a0 = fmaf(sd0, f0[0], a0);
            a1 = fmaf(sd0, f0[1], a1);
            a2 = fmaf(sd0, f0[2], a2);
            a3 = fmaf(sd0, f0[3], a3);
            a0 = fmaf(sd1, f1[0], a0);
            a1 = fmaf(sd1, f1[1], a1);
            a2 = fmaf(sd1, f1[2], a2);
            a3 = fmaf(sd1, f1[3], a3);
        }
        // combine the 4 edge sub-groups
        a0 += __shfl_xor(a0, 16); a0 += __shfl_xor(a0, 32);
        a1 += __shfl_xor(a1, 16); a1 += __shfl_xor(a1, 32);
        a2 += __shfl_xor(a2, 16); a2 += __shfl_xor(a2, 32);
        a3 += __shfl_xor(a3, 16); a3 += __shfl_xor(a3, 32);
        const int c = bb * 64 + nd;
        if (c < NN) {
            float d = disS[nd];
            float dS = d * INVS0;
            float coef = fmaf(d, w[nd], d * d);
            uint sv = *reinterpret_cast<const uint*>(h8 + ((size_t)c << 6) + (l16 << 2));
            float fc[4];
            dec4fp8(sv, fc);
            float g0 = fmaf(dS, fmaf(d, fc[0], a0), blv.x);
            float g1 = fmaf(dS, fmaf(d, fc[1], a1), blv.y);
            float g2 = fmaf(dS, fmaf(d, fc[2], a2), blv.z);
            float g3 = fmaf(dS, fmaf(d, fc[3], a3), blv.w);
            sacc0 = fmaf(coef, fmaxf(g0, 0.f), sacc0);
            sacc1 = fmaf(coef, fmaxf(g1, 0.f), sacc1);
            sacc2 = fmaf(coef, fmaxf(g2, 0.f), sacc2);
            sacc3 = fmaf(coef, fmaxf(g3, 0.f), sacc3);
        }
    }
    if (g4 == 0) {
        red[wv][(l16 << 2) + 0] = sacc0;
        red[wv][(l16 << 2) + 1] = sacc1;
        red[wv][(l16 << 2) + 2] = sacc2;
        red[wv][(l16 << 2) + 3] = sacc3;
    }
    __syncthreads();
    if (wv == 0) {
        float s = ((red[0][lane] + red[1][lane]) + (red[2][lane] + red[3][lane])) +
                  ((red[4][lane] + red[5][lane]) + (red[6][lane] + red[7][lane]));
        atomicAdd(&svec[lane], s);
    }
}

// ---------------- output + fused finalize --------------------------------------
__global__ __launch_bounds__(256) void out_final(const float* __restrict__ H,
    const float* __restrict__ bnsum, const float* __restrict__ bnsumsq,
    const float* __restrict__ gamma, const float* __restrict__ beta,
    const float* __restrict__ svec, const float* __restrict__ g2W,
    const float* __restrict__ g2b, const float* __restrict__ fc1W,
    const float* __restrict__ fc1b, const float* __restrict__ fc2W,
    const float* __restrict__ fc2b, float* __restrict__ out)
{
    __shared__ float scaleS[64], shiftS[64], vdnnS[64];
    __shared__ float consS;
    const int tid = threadIdx.x;
    const int lane = tid & 63;
    const int grp = tid >> 6;
    if (tid < 64) {                              // wave 0 computes finalize
        int j = tid;
        float mu = bnsum[j] * (1.0f / NB);
        float var = bnsumsq[j] * (1.0f / NB) - mu * mu;
        float sc = rsqrtf(var + 1e-5f) * gamma[j];
        scaleS[j] = sc;
        shiftS[j] = beta[j] - mu * sc;
        float ge = 0.f;
        for (int k = 0; k < 64; ++k) ge += svec[k] * g2W[k * 64 + j];
        ge = ge * (1.0f / NN) + g2b[j];
        float vd = 0.f, vg = 0.f;
        for (int k = 0; k < 64; ++k) {
            vd += fc1W[j * 64 + k] * fc2W[k];
            vg += fc1W[(64 + j) * 64 + k] * fc2W[k];
        }
        vdnnS[j] = vd;
        float part = ge * vg + fc1b[j] * fc2W[j];
#pragma unroll
        for (int o = 32; o > 0; o >>= 1) part += __shfl_down(part, o);
        if (j == 0) consS = part + fc2b[0];
    }
    __syncthreads();
    const float sc = scaleS[lane], sh = shiftS[lane], vd = vdnnS[lane];
    const float C = consS;
#pragma unroll 1
    for (int t = 0; t < 8; ++t) {
        int i = blockIdx.x * 32 + grp * 8 + t;
        float x = H[(size_t)i * 64 + lane] * sc + sh;
        x = fmaxf(x, 0.f) * vd;
#pragma unroll
        for (int o = 32; o > 0; o >>= 1) x += __shfl_down(x, o);
        if (lane == 0) out[i] = x + C;
    }
}

extern "C" void kernel_launch(void* const* d_in, const int* in_sizes, int n_in,
                              void* d_out, int out_size, void* d_ws, size_t ws_size,
                              hipStream_t stream)
{
    const float* x1    = (const float*)d_in[0];
    const float* x2    = (const float*)d_in[1];
    const int*   ei    = (const int*)d_in[2];
    const float* dnnW  = (const float*)d_in[3];
    // d_in[4] = dnn_b: cancels inside BatchNorm, unused
    const float* gamma = (const float*)d_in[5];
    const float* beta  = (const float*)d_in[6];
    const float* g1W   = (const float*)d_in[7];
    const float* g1b   = (const float*)d_in[8];
    const float* g2W   = (const float*)d_in[9];
    const float* g2b   = (const float*)d_in[10];
    const float* fc1W  = (const float*)d_in[11];
    const float* fc1b  = (const float*)d_in[12];
    const float* fc2W  = (const float*)d_in[13];
    const float* fc2b  = (const float*)d_in[14];

    float* ws      = (float*)d_ws;
    uchar* h8      = (uchar*)ws;                  // 50176*64 B = 802,816 floats
    float* hdnn    = ws + 1605632;                // 1,048,576 f (layout kept)
    float* dis     = hdnn + 1048576;              // 50,176 f
    int*   cnth    = (int*)(dis + 50176 + 25088); // 50,176 i
    uint*  bufC    = (uint*)(cnth + 50176);       // 784*1280 = 1,003,520
    uint*  bufR    = bufC + NBKT * BCAP;          // 1,003,520
    int*   gcurC   = (int*)(bufR + NBKT * BCAP);  // 784   <- zero region start
    int*   gcurR   = gcurC + NBKT;                // 784
    float* bnsum   = (float*)(gcurR + NBKT);      // 64
    float* bnsumsq = bnsum + 64;                  // 64
    float* svec    = bnsumsq + 64;                // 64    <- zero region end (1760)

    zero_kernel<<<1, 256, 0, stream>>>(gcurC, NBKT * 2 + 192);

    mega<<<P1B + DNNB + NBKT, 512, 0, stream>>>(ei, bufC, bufR, gcurC, gcurR,
                                                x1, dnnW, hdnn, bnsum, bnsumsq,
                                                x2, g1W, h8);
    cnt_dis<<<NBKT, 256, 0, stream>>>(bufC, gcurC, dis, cnth);
    gather_pass<<<NBKT, 512, 0, stream>>>(bufC, gcurC, cnth, bufR, gcurR,
                                          dis, h8, g1b, svec);
    out_final<<<512, 256, 0, stream>>>(hdnn, bnsum, bnsumsq, gamma, beta, svec,
                                       g2W, g2b, fc1W, fc1b, fc2W, fc2b,
                                       (float*)d_out);
}